// Round 16
// baseline (99.402 us; speedup 1.0000x reference)
//
#include <hip/hip_runtime.h>
#include <hip/hip_bf16.h>

// out[b][c] = kxx_mean[b] + kyy[c] - 2*kxy_mean[b][c]
// x[32768][64] f32, atoms[64][32][64] f32, out[256][64] f32.
// R16: occupancy push. No Axch (kxx B re-read from x; A-layout==B-layout),
// LDS ~7.8KB, __launch_bounds__(256,8) -> target 8 waves/SIMD (2x r15).
// Loop = r15 barrier-free global->reg with 2-deep prefetch (validated).

constexpr int   NODES = 128;
constexpr int   DD    = 64;
constexpr int   CC    = 64;
constexpr int   KK    = 32;
constexpr float GAMMA = 1.0f / 64.0f;
constexpr float LOG2E = 1.4426950408889634f;
constexpr float C1    = 2.0f * GAMMA * LOG2E;   // exp2-domain scale on S
constexpr float GL    = GAMMA * LOG2E;

typedef __attribute__((ext_vector_type(8)))  short short8;
typedef __attribute__((ext_vector_type(16))) float f32x16;

#define MFMA(a, b, c) __builtin_amdgcn_mfma_f32_32x32x16_bf16((a), (b), (c), 0, 0, 0)

__device__ __forceinline__ float fexp2(float x) {
#if __has_builtin(__builtin_amdgcn_exp2f)
    return __builtin_amdgcn_exp2f(x);   // compiler-visible: MFMA->VALU hazards handled
#else
    return exp2f(x);
#endif
}

__device__ __forceinline__ unsigned short f2bf(float f) {
    union { float f; unsigned int u; } a; a.f = f;
    unsigned int u = a.u;
    return (unsigned short)((u + 0x7FFFu + ((u >> 16) & 1u)) >> 16);  // RNE
}

// ---------------------------------------------------------------------------
// prep_atoms (r13 verbatim): bfrag C1-scaled, can = -GL*||a||^2, kyy exact.
// B entry: lane l holds col (l&31), k = kt*16+(l>>5)*8+j, bfrag[c*256+kt*64+l].
// ---------------------------------------------------------------------------
__global__ __launch_bounds__(256) void prep_atoms(const float* __restrict__ atoms,
                                                  short8* __restrict__ bfrag,
                                                  float* __restrict__ can,
                                                  float* __restrict__ kyy) {
    const int c = blockIdx.x, t = threadIdx.x;
    __shared__ float a[KK][DD + 1];
    __shared__ float an[KK];
    __shared__ float wred[4];

    const float* ac = atoms + (size_t)c * KK * DD;
    for (int i = t; i < KK * DD; i += 256) a[i >> 6][i & 63] = ac[i];
    __syncthreads();

    if (t < KK) {
        float s = 0.f;
#pragma unroll
        for (int d = 0; d < DD; ++d) s = fmaf(a[t][d], a[t][d], s);
        an[t] = s;
        can[c * KK + t] = -GL * s;
    }
    __syncthreads();

    {   // fragment emit (scaled by C1)
        const int wv = t >> 6, l = t & 63;
        const int kp = l & 31, khh = l >> 5;
        short8 h;
#pragma unroll
        for (int j = 0; j < 8; ++j)
            h[j] = (short)f2bf(C1 * a[kp][wv * 16 + khh * 8 + j]);
        bfrag[(size_t)c * 256 + wv * 64 + l] = h;
    }

    {   // kyy (exact f32)
        const int i = t >> 3, j0 = (t & 7) * 4;
        float s0 = 0, s1 = 0, s2 = 0, s3 = 0;
        for (int d = 0; d < DD; ++d) {
            const float aid = a[i][d];
            s0 = fmaf(aid, a[j0 + 0][d], s0);
            s1 = fmaf(aid, a[j0 + 1][d], s1);
            s2 = fmaf(aid, a[j0 + 2][d], s2);
            s3 = fmaf(aid, a[j0 + 3][d], s3);
        }
        const float ani = an[i];
        float s = fexp2(-GL * (ani + an[j0 + 0] - 2.f * s0))
                + fexp2(-GL * (ani + an[j0 + 1] - 2.f * s1))
                + fexp2(-GL * (ani + an[j0 + 2] - 2.f * s2))
                + fexp2(-GL * (ani + an[j0 + 3] - 2.f * s3));
#pragma unroll
        for (int off = 32; off; off >>= 1) s += __shfl_xor(s, off);
        if ((t & 63) == 0) wred[t >> 6] = s;
    }
    __syncthreads();
    if (t == 0) kyy[c] = (wred[0] + wred[1] + wred[2] + wred[3]) * (1.0f / (KK * KK));
}

// ---------------------------------------------------------------------------
// mmd_fused: grid 1024 = (b, cq), block 256 = 4 waves, wave w = rowtile w.
// LDS ~7.8KB, launch_bounds(256,8): target 8 blocks/CU = 8 waves/SIMD.
// kxx: B-tiles re-read from x in A-build pattern (p==w reuses A registers).
// atoms: 16 tiles, B global->reg, 2-deep prefetch, no loop barriers.
// ---------------------------------------------------------------------------
__global__ __launch_bounds__(256, 8) void mmd_fused(const float* __restrict__ x,
                                                    const short8* __restrict__ bfrag,
                                                    const float* __restrict__ can,
                                                    const float* __restrict__ kyy,
                                                    float* __restrict__ out) {
    const int bid = blockIdx.x, b = bid >> 2, cq = bid & 3;
    const int t = threadIdx.x, w = t >> 6, l = t & 63;
    const int l31 = l & 31, kh = l >> 5;

    __shared__ float part16[4][20][16];   // 5 KB partials
    __shared__ float nl[NODES];           // 512 B: -GL*||x_row||^2
    __shared__ float cavl[16][32];        // 2 KB: -GL*||a||^2 this quarter
    __shared__ float sxy_s[16];
    __shared__ float kxx_s;

    // ---- A-build: rowtile w from x (validated r6/r13 pattern) ----
    const float* xg = x + (size_t)b * NODES * DD;
    float v[32];
    {
        const float* xr = xg + ((size_t)(w * 32 + l31)) * DD + kh * 8;
#pragma unroll
        for (int kt = 0; kt < 4; ++kt) {
            const float4 p0 = *reinterpret_cast<const float4*>(xr + kt * 16);
            const float4 p1 = *reinterpret_cast<const float4*>(xr + kt * 16 + 4);
            v[kt*8+0]=p0.x; v[kt*8+1]=p0.y; v[kt*8+2]=p0.z; v[kt*8+3]=p0.w;
            v[kt*8+4]=p1.x; v[kt*8+5]=p1.y; v[kt*8+6]=p1.z; v[kt*8+7]=p1.w;
        }
    }
    float xn = 0.f;
#pragma unroll
    for (int i = 0; i < 32; ++i) xn = fmaf(v[i], v[i], xn);
    xn += __shfl_xor(xn, 32);
    if (l < 32) nl[w * 32 + l] = -GL * xn;

    short8 A[4];
#pragma unroll
    for (int kt = 0; kt < 4; ++kt) {
        short8 h;
#pragma unroll
        for (int j = 0; j < 8; ++j) h[j] = (short)f2bf(v[kt * 8 + j]);
        A[kt] = h;
    }

    // cav table for this quarter's 16 atoms
    for (int i = t; i < 512; i += 256) cavl[i >> 5][i & 31] = can[cq * 512 + i];

    __syncthreads();                      // barrier 1: nl + cavl ready

    // cx: row-norm constants for this wave's acc rows
    f32x16 cx;
    {
        const float* nb = &nl[w * 32 + 4 * kh];
#pragma unroll
        for (int q = 0; q < 4; ++q) {
            const float4 vq = *reinterpret_cast<const float4*>(nb + 8 * q);
            cx[4*q+0] = vq.x; cx[4*q+1] = vq.y; cx[4*q+2] = vq.z; cx[4*q+3] = vq.w;
        }
    }

    // ---- kxx: 4 tiles; B = x-tile p in A-layout (== B-layout) ----
#pragma unroll
    for (int p = 0; p < 4; ++p) {
        short8 Bt[4];
        if (p == w) {                     // wave-uniform branch: own tile = A
#pragma unroll
            for (int kt = 0; kt < 4; ++kt) Bt[kt] = A[kt];
        } else {
            const float* xc = xg + ((size_t)(p * 32 + l31)) * DD + kh * 8;
#pragma unroll
            for (int kt = 0; kt < 4; ++kt) {
                const float4 q0 = *reinterpret_cast<const float4*>(xc + kt * 16);
                const float4 q1 = *reinterpret_cast<const float4*>(xc + kt * 16 + 4);
                short8 h;
                h[0] = (short)f2bf(q0.x); h[1] = (short)f2bf(q0.y);
                h[2] = (short)f2bf(q0.z); h[3] = (short)f2bf(q0.w);
                h[4] = (short)f2bf(q1.x); h[5] = (short)f2bf(q1.y);
                h[6] = (short)f2bf(q1.z); h[7] = (short)f2bf(q1.w);
                Bt[kt] = h;
            }
        }
        f32x16 acc = {};
#pragma unroll
        for (int kt = 0; kt < 4; ++kt) acc = MFMA(A[kt], Bt[kt], acc);
        const float ec0 = fexp2(nl[p * 32 + l31]);
        float sa = 0.f, sb = 0.f;
#pragma unroll
        for (int r = 0; r < 16; r += 2) {
            sa += fexp2(fmaf(C1, acc[r],     cx[r]));
            sb += fexp2(fmaf(C1, acc[r + 1], cx[r + 1]));
        }
        float ssum = (sa + sb) * ec0;
        ssum += __shfl_xor(ssum, 32);
        ssum += __shfl_xor(ssum, 16);
        if (l < 16) part16[w][p][l] = ssum;
    }

    // ---- atoms: 16 tiles, B global->reg, 2-deep prefetch, no barriers ----
    const short8* bq = bfrag + (size_t)(cq * 16) * 256;
    short8 Breg[2][4];
#pragma unroll
    for (int kt = 0; kt < 4; ++kt) {
        Breg[0][kt] = bq[kt * 64 + l];
        Breg[1][kt] = bq[256 + kt * 64 + l];
    }
#pragma unroll
    for (int j = 0; j < 16; ++j) {
        const float ca = cavl[j][l31];
        f32x16 acc;
#pragma unroll
        for (int r = 0; r < 16; ++r) acc[r] = cx[r] + ca;
#pragma unroll
        for (int kt = 0; kt < 4; ++kt) acc = MFMA(A[kt], Breg[j & 1][kt], acc);
        if (j < 14) {   // refill consumed slot with tile j+2
#pragma unroll
            for (int kt = 0; kt < 4; ++kt)
                Breg[j & 1][kt] = bq[(size_t)(j + 2) * 256 + kt * 64 + l];
        }
        float sa = 0.f, sb = 0.f;
#pragma unroll
        for (int r = 0; r < 16; r += 2) {
            sa += fexp2(acc[r]);
            sb += fexp2(acc[r + 1]);
        }
        float ssum = sa + sb;
        ssum += __shfl_xor(ssum, 32);
        ssum += __shfl_xor(ssum, 16);
        if (l < 16) part16[w][4 + j][l] = ssum;
    }

    __syncthreads();                      // barrier 2: part16 complete

    // ---- tail: reduce + direct out ----
    {
        const int o = t >> 4, g = t & 15;   // o = atom 0..15 (slot o+4)
        float s1 = part16[0][4 + o][g] + part16[1][4 + o][g]
                 + part16[2][4 + o][g] + part16[3][4 + o][g];
        s1 += __shfl_xor(s1, 8);
        s1 += __shfl_xor(s1, 4);
        s1 += __shfl_xor(s1, 2);
        s1 += __shfl_xor(s1, 1);
        if (g == 0) sxy_s[o] = s1;
    }
    if (t < 16) {
        float kx = 0.f;
#pragma unroll
        for (int ww = 0; ww < 4; ++ww)
#pragma unroll
            for (int q = 0; q < 4; ++q) kx += part16[ww][q][t];
        kx += __shfl_xor(kx, 8);
        kx += __shfl_xor(kx, 4);
        kx += __shfl_xor(kx, 2);
        kx += __shfl_xor(kx, 1);
        if (t == 0) kxx_s = kx;
    }
    __syncthreads();
    if (t < 16) {
        out[(size_t)b * CC + cq * 16 + t] =
            kxx_s * (1.0f / 16384.0f) + kyy[cq * 16 + t] - sxy_s[t] * (1.0f / 2048.0f);
    }
}

extern "C" void kernel_launch(void* const* d_in, const int* in_sizes, int n_in,
                              void* d_out, int out_size, void* d_ws, size_t ws_size,
                              hipStream_t stream) {
    const float* x     = (const float*)d_in[0];   // [32768, 64]
    const float* atoms = (const float*)d_in[1];   // [64, 32, 64]
    float* out = (float*)d_out;                   // [256, 64]

    char* ws = (char*)d_ws;
    short8* bfrag = (short8*)(ws);                        // 256 KiB
    float*  can   = (float*) (ws + 262144);               // 8 KiB
    float*  kyy   = (float*) (ws + 270336);               // 256 B

    prep_atoms<<<dim3(CC),   dim3(256), 0, stream>>>(atoms, bfrag, can, kyy);
    mmd_fused <<<dim3(1024), dim3(256), 0, stream>>>(x, bfrag, can, kyy, out);
}

// Round 17
// 48.255 us; speedup vs baseline: 2.0599x; 2.0599x over previous
//
#include <hip/hip_runtime.h>
#include <hip/hip_bf16.h>

// out[b][c] = kxx_mean[b] + kyy[c] - 2*kxy_mean[b][c]
// x[32768][64] f32, atoms[64][32][64] f32, out[256][64] f32.
// R17 = r15 (passing, 29.3us) with __launch_bounds__(256,6): clean occupancy
// A/B at 6 waves/SIMD, spill-free (cap ~85 unified regs; r16's (256,8)->32
// VGPR spill confound removed). LDS ~24KB -> 6 blocks/CU matches the cap.

constexpr int   NODES = 128;
constexpr int   DD    = 64;
constexpr int   CC    = 64;
constexpr int   KK    = 32;
constexpr float GAMMA = 1.0f / 64.0f;
constexpr float LOG2E = 1.4426950408889634f;
constexpr float C1    = 2.0f * GAMMA * LOG2E;   // exp2-domain scale on S
constexpr float GL    = GAMMA * LOG2E;

typedef __attribute__((ext_vector_type(8)))  short short8;
typedef __attribute__((ext_vector_type(16))) float f32x16;

#define MFMA(a, b, c) __builtin_amdgcn_mfma_f32_32x32x16_bf16((a), (b), (c), 0, 0, 0)

__device__ __forceinline__ float fexp2(float x) {
#if __has_builtin(__builtin_amdgcn_exp2f)
    return __builtin_amdgcn_exp2f(x);   // compiler-visible: MFMA->VALU hazards handled
#else
    return exp2f(x);
#endif
}

__device__ __forceinline__ unsigned short f2bf(float f) {
    union { float f; unsigned int u; } a; a.f = f;
    unsigned int u = a.u;
    return (unsigned short)((u + 0x7FFFu + ((u >> 16) & 1u)) >> 16);  // RNE
}

// ---------------------------------------------------------------------------
// prep_atoms (r13 verbatim): bfrag C1-scaled, can = -GL*||a||^2, kyy exact.
// B entry: lane l holds col (l&31), k = kt*16+(l>>5)*8+j, bfrag[c*256+kt*64+l].
// ---------------------------------------------------------------------------
__global__ __launch_bounds__(256) void prep_atoms(const float* __restrict__ atoms,
                                                  short8* __restrict__ bfrag,
                                                  float* __restrict__ can,
                                                  float* __restrict__ kyy) {
    const int c = blockIdx.x, t = threadIdx.x;
    __shared__ float a[KK][DD + 1];
    __shared__ float an[KK];
    __shared__ float wred[4];

    const float* ac = atoms + (size_t)c * KK * DD;
    for (int i = t; i < KK * DD; i += 256) a[i >> 6][i & 63] = ac[i];
    __syncthreads();

    if (t < KK) {
        float s = 0.f;
#pragma unroll
        for (int d = 0; d < DD; ++d) s = fmaf(a[t][d], a[t][d], s);
        an[t] = s;
        can[c * KK + t] = -GL * s;
    }
    __syncthreads();

    {   // fragment emit (scaled by C1)
        const int wv = t >> 6, l = t & 63;
        const int kp = l & 31, khh = l >> 5;
        short8 h;
#pragma unroll
        for (int j = 0; j < 8; ++j)
            h[j] = (short)f2bf(C1 * a[kp][wv * 16 + khh * 8 + j]);
        bfrag[(size_t)c * 256 + wv * 64 + l] = h;
    }

    {   // kyy (exact f32)
        const int i = t >> 3, j0 = (t & 7) * 4;
        float s0 = 0, s1 = 0, s2 = 0, s3 = 0;
        for (int d = 0; d < DD; ++d) {
            const float aid = a[i][d];
            s0 = fmaf(aid, a[j0 + 0][d], s0);
            s1 = fmaf(aid, a[j0 + 1][d], s1);
            s2 = fmaf(aid, a[j0 + 2][d], s2);
            s3 = fmaf(aid, a[j0 + 3][d], s3);
        }
        const float ani = an[i];
        float s = fexp2(-GL * (ani + an[j0 + 0] - 2.f * s0))
                + fexp2(-GL * (ani + an[j0 + 1] - 2.f * s1))
                + fexp2(-GL * (ani + an[j0 + 2] - 2.f * s2))
                + fexp2(-GL * (ani + an[j0 + 3] - 2.f * s3));
#pragma unroll
        for (int off = 32; off; off >>= 1) s += __shfl_xor(s, off);
        if ((t & 63) == 0) wred[t >> 6] = s;
    }
    __syncthreads();
    if (t == 0) kyy[c] = (wred[0] + wred[1] + wred[2] + wred[3]) * (1.0f / (KK * KK));
}

// ---------------------------------------------------------------------------
// mmd_fused: grid 1024 = (b, cq), block 256 = 4 waves, wave w = rowtile w.
// r15 body verbatim; only the launch bound changed (256,4)->(256,6).
// ---------------------------------------------------------------------------
__global__ __launch_bounds__(256, 6) void mmd_fused(const float* __restrict__ x,
                                                    const short8* __restrict__ bfrag,
                                                    const float* __restrict__ can,
                                                    const float* __restrict__ kyy,
                                                    float* __restrict__ out) {
    const int bid = blockIdx.x, b = bid >> 2, cq = bid & 3;
    const int t = threadIdx.x, w = t >> 6, l = t & 63;
    const int l31 = l & 31, kh = l >> 5;

    __shared__ short8 Axch[4][256];       // 16 KB A-tile exchange (kxx B operands)
    __shared__ float  part16[4][20][16];  // 5 KB partials
    __shared__ float  nl[NODES];          // 512 B: -GL*||x_row||^2
    __shared__ float  cavl[16][32];       // 2 KB: -GL*||a||^2 this quarter
    __shared__ float  sxy_s[16];
    __shared__ float  kxx_s;

    // ---- A-build: rowtile w from x ----
    float v[32];
    {
        const float* xr = x + ((size_t)(b * NODES + w * 32 + l31)) * DD + kh * 8;
#pragma unroll
        for (int kt = 0; kt < 4; ++kt) {
            const float4 p0 = *reinterpret_cast<const float4*>(xr + kt * 16);
            const float4 p1 = *reinterpret_cast<const float4*>(xr + kt * 16 + 4);
            v[kt*8+0]=p0.x; v[kt*8+1]=p0.y; v[kt*8+2]=p0.z; v[kt*8+3]=p0.w;
            v[kt*8+4]=p1.x; v[kt*8+5]=p1.y; v[kt*8+6]=p1.z; v[kt*8+7]=p1.w;
        }
    }
    float xn = 0.f;
#pragma unroll
    for (int i = 0; i < 32; ++i) xn = fmaf(v[i], v[i], xn);
    xn += __shfl_xor(xn, 32);
    if (l < 32) nl[w * 32 + l] = -GL * xn;

    short8 A[4];
#pragma unroll
    for (int kt = 0; kt < 4; ++kt) {
        short8 h;
#pragma unroll
        for (int j = 0; j < 8; ++j) h[j] = (short)f2bf(v[kt * 8 + j]);
        A[kt] = h;
        Axch[w][kt * 64 + l] = h;         // kxx B-tile (A-layout == B-layout)
    }

    // cav table: -GL*||a||^2 for the 16 atoms of this quarter
    for (int i = t; i < 512; i += 256) cavl[i >> 5][i & 31] = can[cq * 512 + i];

    __syncthreads();                      // barrier 1: nl, Axch, cavl ready

    // cx: row-norm constants for this wave's acc rows
    f32x16 cx;
    {
        const float* nb = &nl[w * 32 + 4 * kh];
#pragma unroll
        for (int q = 0; q < 4; ++q) {
            const float4 vq = *reinterpret_cast<const float4*>(nb + 8 * q);
            cx[4*q+0] = vq.x; cx[4*q+1] = vq.y; cx[4*q+2] = vq.z; cx[4*q+3] = vq.w;
        }
    }

    // ---- kxx: 4 tiles from Axch ----
#pragma unroll
    for (int p = 0; p < 4; ++p) {
        short8 Bt[4];
#pragma unroll
        for (int kt = 0; kt < 4; ++kt) Bt[kt] = Axch[p][kt * 64 + l];
        f32x16 acc = {};
#pragma unroll
        for (int kt = 0; kt < 4; ++kt) acc = MFMA(A[kt], Bt[kt], acc);
        const float ec0 = fexp2(nl[p * 32 + l31]);
        float sa = 0.f, sb = 0.f;
#pragma unroll
        for (int r = 0; r < 16; r += 2) {
            sa += fexp2(fmaf(C1, acc[r],     cx[r]));
            sb += fexp2(fmaf(C1, acc[r + 1], cx[r + 1]));
        }
        float ssum = (sa + sb) * ec0;
        ssum += __shfl_xor(ssum, 32);
        ssum += __shfl_xor(ssum, 16);
        if (l < 16) part16[w][p][l] = ssum;
    }

    // ---- atoms: 16 tiles, B global->reg, 2-deep prefetch, no barriers ----
    const short8* bq = bfrag + (size_t)(cq * 16) * 256;
    short8 Breg[2][4];
#pragma unroll
    for (int kt = 0; kt < 4; ++kt) {
        Breg[0][kt] = bq[kt * 64 + l];
        Breg[1][kt] = bq[256 + kt * 64 + l];
    }
#pragma unroll
    for (int j = 0; j < 16; ++j) {
        const float ca = cavl[j][l31];
        f32x16 acc;
#pragma unroll
        for (int r = 0; r < 16; ++r) acc[r] = cx[r] + ca;
#pragma unroll
        for (int kt = 0; kt < 4; ++kt) acc = MFMA(A[kt], Breg[j & 1][kt], acc);
        if (j < 14) {   // refill the slot just consumed with tile j+2
#pragma unroll
            for (int kt = 0; kt < 4; ++kt)
                Breg[j & 1][kt] = bq[(size_t)(j + 2) * 256 + kt * 64 + l];
        }
        float sa = 0.f, sb = 0.f;
#pragma unroll
        for (int r = 0; r < 16; r += 2) {
            sa += fexp2(acc[r]);
            sb += fexp2(acc[r + 1]);
        }
        float ssum = sa + sb;
        ssum += __shfl_xor(ssum, 32);
        ssum += __shfl_xor(ssum, 16);
        if (l < 16) part16[w][4 + j][l] = ssum;
    }

    __syncthreads();                      // barrier 2: part16 complete

    // ---- tail: reduce + direct out ----
    {
        const int o = t >> 4, g = t & 15;   // o = atom 0..15 (slot o+4)
        float s1 = part16[0][4 + o][g] + part16[1][4 + o][g]
                 + part16[2][4 + o][g] + part16[3][4 + o][g];
        s1 += __shfl_xor(s1, 8);
        s1 += __shfl_xor(s1, 4);
        s1 += __shfl_xor(s1, 2);
        s1 += __shfl_xor(s1, 1);
        if (g == 0) sxy_s[o] = s1;
    }
    if (t < 16) {
        float kx = 0.f;
#pragma unroll
        for (int ww = 0; ww < 4; ++ww)
#pragma unroll
            for (int q = 0; q < 4; ++q) kx += part16[ww][q][t];
        kx += __shfl_xor(kx, 8);
        kx += __shfl_xor(kx, 4);
        kx += __shfl_xor(kx, 2);
        kx += __shfl_xor(kx, 1);
        if (t == 0) kxx_s = kx;
    }
    __syncthreads();
    if (t < 16) {
        out[(size_t)b * CC + cq * 16 + t] =
            kxx_s * (1.0f / 16384.0f) + kyy[cq * 16 + t] - sxy_s[t] * (1.0f / 2048.0f);
    }
}

extern "C" void kernel_launch(void* const* d_in, const int* in_sizes, int n_in,
                              void* d_out, int out_size, void* d_ws, size_t ws_size,
                              hipStream_t stream) {
    const float* x     = (const float*)d_in[0];   // [32768, 64]
    const float* atoms = (const float*)d_in[1];   // [64, 32, 64]
    float* out = (float*)d_out;                   // [256, 64]

    char* ws = (char*)d_ws;
    short8* bfrag = (short8*)(ws);                        // 256 KiB
    float*  can   = (float*) (ws + 262144);               // 8 KiB
    float*  kyy   = (float*) (ws + 270336);               // 256 B

    prep_atoms<<<dim3(CC),   dim3(256), 0, stream>>>(atoms, bfrag, can, kyy);
    mmd_fused <<<dim3(1024), dim3(256), 0, stream>>>(x, bfrag, can, kyy, out);
}

// Round 18
// 32.988 us; speedup vs baseline: 3.0133x; 1.4628x over previous
//
#include <hip/hip_runtime.h>
#include <hip/hip_bf16.h>

// out[b][c] = kxx_mean[b] + kyy[c] - 2*kxy_mean[b][c]
// x[32768][64] f32, atoms[64][32][64] f32, out[256][64] f32.
// R18: 16x16x32 MFMA restructure. acc 4 regs (vs 16), wave = 16-row subtile,
// block = 512 thr (8 waves), natural VGPR ~50-60 -> 8 waves/SIMD with NO
// launch-bounds cap (r16/r17 spill confounds removed). LDS ~18.6KB.
// Same validated algebra: C1-scaled B, acc init = cx+ca, bare-exp epilogue.

constexpr int   NODES = 128;
constexpr int   DD    = 64;
constexpr int   CC    = 64;
constexpr int   KK    = 32;
constexpr float GAMMA = 1.0f / 64.0f;
constexpr float LOG2E = 1.4426950408889634f;
constexpr float C1    = 2.0f * GAMMA * LOG2E;   // exp2-domain scale on S
constexpr float GL    = GAMMA * LOG2E;

typedef __attribute__((ext_vector_type(8)))  short short8;
typedef __attribute__((ext_vector_type(4)))  float f32x4;

#define MFMA16(a, b, c) __builtin_amdgcn_mfma_f32_16x16x32_bf16((a), (b), (c), 0, 0, 0)

__device__ __forceinline__ float fexp2(float x) {
#if __has_builtin(__builtin_amdgcn_exp2f)
    return __builtin_amdgcn_exp2f(x);   // compiler-visible: MFMA->VALU hazards handled
#else
    return exp2f(x);
#endif
}

__device__ __forceinline__ unsigned short f2bf(float f) {
    union { float f; unsigned int u; } a; a.f = f;
    unsigned int u = a.u;
    return (unsigned short)((u + 0x7FFFu + ((u >> 16) & 1u)) >> 16);  // RNE
}

// ---------------------------------------------------------------------------
// prep_atoms: bfrag in 16x16x32 B layout, scaled by C1. can, kyy unchanged.
// B entry: lane l holds col ct*16+(l&15), k = kt*32+(l>>4)*8+j.
// bfrag[((c*2+ct)*2+kt)*64 + l]; 4 frag-groups per atom = 4 waves.
// ---------------------------------------------------------------------------
__global__ __launch_bounds__(256) void prep_atoms(const float* __restrict__ atoms,
                                                  short8* __restrict__ bfrag,
                                                  float* __restrict__ can,
                                                  float* __restrict__ kyy) {
    const int c = blockIdx.x, t = threadIdx.x;
    __shared__ float a[KK][DD + 1];
    __shared__ float an[KK];
    __shared__ float wred[4];

    const float* ac = atoms + (size_t)c * KK * DD;
    for (int i = t; i < KK * DD; i += 256) a[i >> 6][i & 63] = ac[i];
    __syncthreads();

    if (t < KK) {
        float s = 0.f;
#pragma unroll
        for (int d = 0; d < DD; ++d) s = fmaf(a[t][d], a[t][d], s);
        an[t] = s;
        can[c * KK + t] = -GL * s;
    }
    __syncthreads();

    {   // fragment emit: wave wv -> (ct = wv>>1, kt = wv&1)
        const int wv = t >> 6, l = t & 63;
        const int ct = wv >> 1, kt = wv & 1;
        const int kp = ct * 16 + (l & 15);
        const int d0 = kt * 32 + (l >> 4) * 8;
        short8 h;
#pragma unroll
        for (int j = 0; j < 8; ++j) h[j] = (short)f2bf(C1 * a[kp][d0 + j]);
        bfrag[((size_t)(c * 2 + ct) * 2 + kt) * 64 + l] = h;
    }

    {   // kyy (exact f32)
        const int i = t >> 3, j0 = (t & 7) * 4;
        float s0 = 0, s1 = 0, s2 = 0, s3 = 0;
        for (int d = 0; d < DD; ++d) {
            const float aid = a[i][d];
            s0 = fmaf(aid, a[j0 + 0][d], s0);
            s1 = fmaf(aid, a[j0 + 1][d], s1);
            s2 = fmaf(aid, a[j0 + 2][d], s2);
            s3 = fmaf(aid, a[j0 + 3][d], s3);
        }
        const float ani = an[i];
        float s = fexp2(-GL * (ani + an[j0 + 0] - 2.f * s0))
                + fexp2(-GL * (ani + an[j0 + 1] - 2.f * s1))
                + fexp2(-GL * (ani + an[j0 + 2] - 2.f * s2))
                + fexp2(-GL * (ani + an[j0 + 3] - 2.f * s3));
#pragma unroll
        for (int off = 32; off; off >>= 1) s += __shfl_xor(s, off);
        if ((t & 63) == 0) wred[t >> 6] = s;
    }
    __syncthreads();
    if (t == 0) kyy[c] = (wred[0] + wred[1] + wred[2] + wred[3]) * (1.0f / (KK * KK));
}

// ---------------------------------------------------------------------------
// mmd_fused: grid 1024 = (b, cq), block 512 = 8 waves, wave w = rows
// w*16..w*16+15. A[kt] = 2 frags (8 VGPR). kxx: 8 col-subtiles from Axch,
// scalar accumulator in regs. atoms: 16 tiles, B global->reg (4 frags),
// acc init = cx+ca, bare exp. part[] aliases Axch after barrier 2.
// A/B lane maps: A row=l&15 k=(l>>4)*8+j; B col=l&15 same k.
// C/D: col=l&15, row=(l>>4)*4+ri (guide, m89-verified).
// ---------------------------------------------------------------------------
__global__ __launch_bounds__(512) void mmd_fused(const float* __restrict__ x,
                                                 const short8* __restrict__ bfrag,
                                                 const float* __restrict__ can,
                                                 const float* __restrict__ kyy,
                                                 float* __restrict__ out) {
    const int bid = blockIdx.x, b = bid >> 2, cq = bid & 3;
    const int t = threadIdx.x, w = t >> 6, l = t & 63;
    const int l15 = l & 15, lh = l >> 4;

    __shared__ short8 Axch[8][2][64];     // 16 KB; aliased by part[] after kxx
    __shared__ float  nl[NODES];          // 512 B: -GL*||x_row||^2
    __shared__ float  cavl[16][KK];       // 2 KB: -GL*||a||^2 this quarter

    // ---- A-build: 16 rows (w*16 + l15), both K-chunks ----
    const float* xg = x + (size_t)b * NODES * DD;
    short8 A[2];
    float np = 0.f;
    {
        const float* xr = xg + (size_t)(w * 16 + l15) * DD;
#pragma unroll
        for (int kt = 0; kt < 2; ++kt) {
            const int d0 = kt * 32 + lh * 8;
            const float4 p0 = *reinterpret_cast<const float4*>(xr + d0);
            const float4 p1 = *reinterpret_cast<const float4*>(xr + d0 + 4);
            const float vv[8] = {p0.x, p0.y, p0.z, p0.w, p1.x, p1.y, p1.z, p1.w};
            short8 h;
#pragma unroll
            for (int j = 0; j < 8; ++j) {
                np = fmaf(vv[j], vv[j], np);
                h[j] = (short)f2bf(vv[j]);
            }
            A[kt] = h;
            Axch[w][kt][l] = h;           // kxx B-tile (A-layout == B-layout)
        }
    }
    np += __shfl_xor(np, 16);             // reduce over lh (lanes sharing l15)
    np += __shfl_xor(np, 32);
    if (l < 16) nl[w * 16 + l15] = -GL * np;

    // cav table for this quarter's 16 atoms
    for (int i = t; i < 512; i += 512) cavl[i >> 5][i & 31] = can[cq * 512 + i];

    __syncthreads();                      // barrier 1: Axch, nl, cavl ready

    // cx: this lane's 4 acc-row constants (rows w*16 + lh*4 + ri)
    f32x4 cxv;
#pragma unroll
    for (int ri = 0; ri < 4; ++ri) cxv[ri] = nl[w * 16 + lh * 4 + ri];

    // ---- kxx: 8 col-subtiles, scalar accumulate in regs ----
    float kxxacc = 0.f;
#pragma unroll
    for (int ct8 = 0; ct8 < 8; ++ct8) {
        const short8 Bt0 = Axch[ct8][0][l];
        const short8 Bt1 = Axch[ct8][1][l];
        f32x4 acc = {};
        acc = MFMA16(A[0], Bt0, acc);
        acc = MFMA16(A[1], Bt1, acc);
        const float ecc = fexp2(nl[ct8 * 16 + l15]);
        float s4 = fexp2(fmaf(C1, acc[0], cxv[0]))
                 + fexp2(fmaf(C1, acc[1], cxv[1]))
                 + fexp2(fmaf(C1, acc[2], cxv[2]))
                 + fexp2(fmaf(C1, acc[3], cxv[3]));
        kxxacc = fmaf(s4, ecc, kxxacc);
    }

    __syncthreads();                      // barrier 2: Axch reads done -> alias OK
    float* part = (float*)&Axch[0][0][0]; // part[w*16+j] atoms; part[128+w] kxx

    {   // kxx reduce + stash
        float s = kxxacc;
        s += __shfl_xor(s, 32);
        s += __shfl_xor(s, 16);
        s += __shfl_xor(s, 8);
        s += __shfl_xor(s, 4);
        s += __shfl_xor(s, 2);
        s += __shfl_xor(s, 1);
        if (l == 0) part[128 + w] = s;
    }

    // ---- atoms: 16 tiles, B global->reg, no barriers ----
    const short8* bq = bfrag + (size_t)(cq * 16) * 256;
#pragma unroll
    for (int j = 0; j < 16; ++j) {
        const short8* src = bq + (size_t)j * 256;
        short8 B00 = src[l];              // (ct0,kt0)
        short8 B01 = src[64 + l];         // (ct0,kt1)
        short8 B10 = src[128 + l];        // (ct1,kt0)
        short8 B11 = src[192 + l];        // (ct1,kt1)

        const float ca0 = cavl[j][l15];
        const float ca1 = cavl[j][16 + l15];

        f32x4 acc0, acc1;
#pragma unroll
        for (int ri = 0; ri < 4; ++ri) { acc0[ri] = cxv[ri] + ca0; acc1[ri] = cxv[ri] + ca1; }
        acc0 = MFMA16(A[0], B00, acc0);
        acc1 = MFMA16(A[0], B10, acc1);
        acc0 = MFMA16(A[1], B01, acc0);
        acc1 = MFMA16(A[1], B11, acc1);

        float s = fexp2(acc0[0]) + fexp2(acc0[1]) + fexp2(acc0[2]) + fexp2(acc0[3])
                + fexp2(acc1[0]) + fexp2(acc1[1]) + fexp2(acc1[2]) + fexp2(acc1[3]);
        s += __shfl_xor(s, 32);
        s += __shfl_xor(s, 16);
        s += __shfl_xor(s, 8);
        s += __shfl_xor(s, 4);
        s += __shfl_xor(s, 2);
        s += __shfl_xor(s, 1);
        if (l == 0) part[w * 16 + j] = s;
    }

    __syncthreads();                      // barrier 3: part complete

    if (t < 16) {
        float sxy = 0.f;
#pragma unroll
        for (int ww = 0; ww < 8; ++ww) sxy += part[ww * 16 + t];
        float kxx = 0.f;
#pragma unroll
        for (int ww = 0; ww < 8; ++ww) kxx += part[128 + ww];
        out[(size_t)b * CC + cq * 16 + t] =
            kxx * (1.0f / 16384.0f) + kyy[cq * 16 + t] - sxy * (1.0f / 2048.0f);
    }
}

extern "C" void kernel_launch(void* const* d_in, const int* in_sizes, int n_in,
                              void* d_out, int out_size, void* d_ws, size_t ws_size,
                              hipStream_t stream) {
    const float* x     = (const float*)d_in[0];   // [32768, 64]
    const float* atoms = (const float*)d_in[1];   // [64, 32, 64]
    float* out = (float*)d_out;                   // [256, 64]

    char* ws = (char*)d_ws;
    short8* bfrag = (short8*)(ws);                        // 256 KiB
    float*  can   = (float*) (ws + 262144);               // 8 KiB
    float*  kyy   = (float*) (ws + 270336);               // 256 B

    prep_atoms<<<dim3(CC),   dim3(256), 0, stream>>>(atoms, bfrag, can, kyy);
    mmd_fused <<<dim3(1024), dim3(512), 0, stream>>>(x, bfrag, can, kyy, out);
}

// Round 19
// 29.330 us; speedup vs baseline: 3.3891x; 1.1247x over previous
//
#include <hip/hip_runtime.h>
#include <hip/hip_bf16.h>

// out[b][c] = kxx_mean[b] + kyy[c] - 2*kxy_mean[b][c]
// x[32768][64] f32, atoms[64][32][64] f32, out[256][64] f32.
// R19 = r15 verbatim (session best: 29.29us, absmax 2.441e-4).
// Barrier-free main loop: B global->reg 2-deep prefetch, kxx via one LDS
// A-exchange, single-pass bf16 MFMA, C1-scaled B, acc-init = cx+ca,
// bare-exp epilogue. 4 waves/SIMD (higher occupancy A/B'd: no gain, r18).

constexpr int   NODES = 128;
constexpr int   DD    = 64;
constexpr int   CC    = 64;
constexpr int   KK    = 32;
constexpr float GAMMA = 1.0f / 64.0f;
constexpr float LOG2E = 1.4426950408889634f;
constexpr float C1    = 2.0f * GAMMA * LOG2E;   // exp2-domain scale on S
constexpr float GL    = GAMMA * LOG2E;

typedef __attribute__((ext_vector_type(8)))  short short8;
typedef __attribute__((ext_vector_type(16))) float f32x16;

#define MFMA(a, b, c) __builtin_amdgcn_mfma_f32_32x32x16_bf16((a), (b), (c), 0, 0, 0)

__device__ __forceinline__ float fexp2(float x) {
#if __has_builtin(__builtin_amdgcn_exp2f)
    return __builtin_amdgcn_exp2f(x);   // compiler-visible: MFMA->VALU hazards handled
#else
    return exp2f(x);
#endif
}

__device__ __forceinline__ unsigned short f2bf(float f) {
    union { float f; unsigned int u; } a; a.f = f;
    unsigned int u = a.u;
    return (unsigned short)((u + 0x7FFFu + ((u >> 16) & 1u)) >> 16);  // RNE
}

// ---------------------------------------------------------------------------
// prep_atoms: bfrag C1-scaled, can = -GL*||a||^2, kyy exact.
// B entry: lane l holds col (l&31), k = kt*16+(l>>5)*8+j, bfrag[c*256+kt*64+l].
// ---------------------------------------------------------------------------
__global__ __launch_bounds__(256) void prep_atoms(const float* __restrict__ atoms,
                                                  short8* __restrict__ bfrag,
                                                  float* __restrict__ can,
                                                  float* __restrict__ kyy) {
    const int c = blockIdx.x, t = threadIdx.x;
    __shared__ float a[KK][DD + 1];
    __shared__ float an[KK];
    __shared__ float wred[4];

    const float* ac = atoms + (size_t)c * KK * DD;
    for (int i = t; i < KK * DD; i += 256) a[i >> 6][i & 63] = ac[i];
    __syncthreads();

    if (t < KK) {
        float s = 0.f;
#pragma unroll
        for (int d = 0; d < DD; ++d) s = fmaf(a[t][d], a[t][d], s);
        an[t] = s;
        can[c * KK + t] = -GL * s;
    }
    __syncthreads();

    {   // fragment emit (scaled by C1)
        const int wv = t >> 6, l = t & 63;
        const int kp = l & 31, khh = l >> 5;
        short8 h;
#pragma unroll
        for (int j = 0; j < 8; ++j)
            h[j] = (short)f2bf(C1 * a[kp][wv * 16 + khh * 8 + j]);
        bfrag[(size_t)c * 256 + wv * 64 + l] = h;
    }

    {   // kyy (exact f32)
        const int i = t >> 3, j0 = (t & 7) * 4;
        float s0 = 0, s1 = 0, s2 = 0, s3 = 0;
        for (int d = 0; d < DD; ++d) {
            const float aid = a[i][d];
            s0 = fmaf(aid, a[j0 + 0][d], s0);
            s1 = fmaf(aid, a[j0 + 1][d], s1);
            s2 = fmaf(aid, a[j0 + 2][d], s2);
            s3 = fmaf(aid, a[j0 + 3][d], s3);
        }
        const float ani = an[i];
        float s = fexp2(-GL * (ani + an[j0 + 0] - 2.f * s0))
                + fexp2(-GL * (ani + an[j0 + 1] - 2.f * s1))
                + fexp2(-GL * (ani + an[j0 + 2] - 2.f * s2))
                + fexp2(-GL * (ani + an[j0 + 3] - 2.f * s3));
#pragma unroll
        for (int off = 32; off; off >>= 1) s += __shfl_xor(s, off);
        if ((t & 63) == 0) wred[t >> 6] = s;
    }
    __syncthreads();
    if (t == 0) kyy[c] = (wred[0] + wred[1] + wred[2] + wred[3]) * (1.0f / (KK * KK));
}

// ---------------------------------------------------------------------------
// mmd_fused: grid 1024 = (b, cq), block 256 = 4 waves, wave w = rowtile w.
// Prologue: A-build from x + norms + A->LDS exchange + cav table; barrier.
// kxx: 4 tiles, B = Axch[p]. atoms: 16 tiles, B global->reg, 2-deep
// prefetch, NO loop barriers. One barrier before tail reduce; direct out.
// ---------------------------------------------------------------------------
__global__ __launch_bounds__(256, 4) void mmd_fused(const float* __restrict__ x,
                                                    const short8* __restrict__ bfrag,
                                                    const float* __restrict__ can,
                                                    const float* __restrict__ kyy,
                                                    float* __restrict__ out) {
    const int bid = blockIdx.x, b = bid >> 2, cq = bid & 3;
    const int t = threadIdx.x, w = t >> 6, l = t & 63;
    const int l31 = l & 31, kh = l >> 5;

    __shared__ short8 Axch[4][256];       // 16 KB A-tile exchange (kxx B operands)
    __shared__ float  part16[4][20][16];  // 5 KB partials
    __shared__ float  nl[NODES];          // 512 B: -GL*||x_row||^2
    __shared__ float  cavl[16][32];       // 2 KB: -GL*||a||^2 this quarter
    __shared__ float  sxy_s[16];
    __shared__ float  kxx_s;

    // ---- A-build: rowtile w from x ----
    float v[32];
    {
        const float* xr = x + ((size_t)(b * NODES + w * 32 + l31)) * DD + kh * 8;
#pragma unroll
        for (int kt = 0; kt < 4; ++kt) {
            const float4 p0 = *reinterpret_cast<const float4*>(xr + kt * 16);
            const float4 p1 = *reinterpret_cast<const float4*>(xr + kt * 16 + 4);
            v[kt*8+0]=p0.x; v[kt*8+1]=p0.y; v[kt*8+2]=p0.z; v[kt*8+3]=p0.w;
            v[kt*8+4]=p1.x; v[kt*8+5]=p1.y; v[kt*8+6]=p1.z; v[kt*8+7]=p1.w;
        }
    }
    float xn = 0.f;
#pragma unroll
    for (int i = 0; i < 32; ++i) xn = fmaf(v[i], v[i], xn);
    xn += __shfl_xor(xn, 32);
    if (l < 32) nl[w * 32 + l] = -GL * xn;

    short8 A[4];
#pragma unroll
    for (int kt = 0; kt < 4; ++kt) {
        short8 h;
#pragma unroll
        for (int j = 0; j < 8; ++j) h[j] = (short)f2bf(v[kt * 8 + j]);
        A[kt] = h;
        Axch[w][kt * 64 + l] = h;         // kxx B-tile (A-layout == B-layout)
    }

    // cav table: -GL*||a||^2 for the 16 atoms of this quarter
    for (int i = t; i < 512; i += 256) cavl[i >> 5][i & 31] = can[cq * 512 + i];

    __syncthreads();                      // barrier 1: nl, Axch, cavl ready

    // cx: row-norm constants for this wave's acc rows
    f32x16 cx;
    {
        const float* nb = &nl[w * 32 + 4 * kh];
#pragma unroll
        for (int q = 0; q < 4; ++q) {
            const float4 vq = *reinterpret_cast<const float4*>(nb + 8 * q);
            cx[4*q+0] = vq.x; cx[4*q+1] = vq.y; cx[4*q+2] = vq.z; cx[4*q+3] = vq.w;
        }
    }

    // ---- kxx: 4 tiles from Axch ----
#pragma unroll
    for (int p = 0; p < 4; ++p) {
        short8 Bt[4];
#pragma unroll
        for (int kt = 0; kt < 4; ++kt) Bt[kt] = Axch[p][kt * 64 + l];
        f32x16 acc = {};
#pragma unroll
        for (int kt = 0; kt < 4; ++kt) acc = MFMA(A[kt], Bt[kt], acc);
        const float ec0 = fexp2(nl[p * 32 + l31]);
        float sa = 0.f, sb = 0.f;
#pragma unroll
        for (int r = 0; r < 16; r += 2) {
            sa += fexp2(fmaf(C1, acc[r],     cx[r]));
            sb += fexp2(fmaf(C1, acc[r + 1], cx[r + 1]));
        }
        float ssum = (sa + sb) * ec0;
        ssum += __shfl_xor(ssum, 32);
        ssum += __shfl_xor(ssum, 16);
        if (l < 16) part16[w][p][l] = ssum;
    }

    // ---- atoms: 16 tiles, B global->reg, 2-deep prefetch, no barriers ----
    const short8* bq = bfrag + (size_t)(cq * 16) * 256;
    short8 Breg[2][4];
#pragma unroll
    for (int kt = 0; kt < 4; ++kt) {
        Breg[0][kt] = bq[kt * 64 + l];
        Breg[1][kt] = bq[256 + kt * 64 + l];
    }
#pragma unroll
    for (int j = 0; j < 16; ++j) {
        const float ca = cavl[j][l31];
        f32x16 acc;
#pragma unroll
        for (int r = 0; r < 16; ++r) acc[r] = cx[r] + ca;
#pragma unroll
        for (int kt = 0; kt < 4; ++kt) acc = MFMA(A[kt], Breg[j & 1][kt], acc);
        if (j < 14) {   // refill the slot just consumed with tile j+2
#pragma unroll
            for (int kt = 0; kt < 4; ++kt)
                Breg[j & 1][kt] = bq[(size_t)(j + 2) * 256 + kt * 64 + l];
        }
        float sa = 0.f, sb = 0.f;
#pragma unroll
        for (int r = 0; r < 16; r += 2) {
            sa += fexp2(acc[r]);
            sb += fexp2(acc[r + 1]);
        }
        float ssum = sa + sb;
        ssum += __shfl_xor(ssum, 32);
        ssum += __shfl_xor(ssum, 16);
        if (l < 16) part16[w][4 + j][l] = ssum;
    }

    __syncthreads();                      // barrier 2: part16 complete

    // ---- tail: reduce + direct out ----
    {
        const int o = t >> 4, g = t & 15;   // o = atom 0..15 (slot o+4)
        float s1 = part16[0][4 + o][g] + part16[1][4 + o][g]
                 + part16[2][4 + o][g] + part16[3][4 + o][g];
        s1 += __shfl_xor(s1, 8);
        s1 += __shfl_xor(s1, 4);
        s1 += __shfl_xor(s1, 2);
        s1 += __shfl_xor(s1, 1);
        if (g == 0) sxy_s[o] = s1;
    }
    if (t < 16) {
        float kx = 0.f;
#pragma unroll
        for (int ww = 0; ww < 4; ++ww)
#pragma unroll
            for (int q = 0; q < 4; ++q) kx += part16[ww][q][t];
        kx += __shfl_xor(kx, 8);
        kx += __shfl_xor(kx, 4);
        kx += __shfl_xor(kx, 2);
        kx += __shfl_xor(kx, 1);
        if (t == 0) kxx_s = kx;
    }
    __syncthreads();
    if (t < 16) {
        out[(size_t)b * CC + cq * 16 + t] =
            kxx_s * (1.0f / 16384.0f) + kyy[cq * 16 + t] - sxy_s[t] * (1.0f / 2048.0f);
    }
}

extern "C" void kernel_launch(void* const* d_in, const int* in_sizes, int n_in,
                              void* d_out, int out_size, void* d_ws, size_t ws_size,
                              hipStream_t stream) {
    const float* x     = (const float*)d_in[0];   // [32768, 64]
    const float* atoms = (const float*)d_in[1];   // [64, 32, 64]
    float* out = (float*)d_out;                   // [256, 64]

    char* ws = (char*)d_ws;
    short8* bfrag = (short8*)(ws);                        // 256 KiB
    float*  can   = (float*) (ws + 262144);               // 8 KiB
    float*  kyy   = (float*) (ws + 270336);               // 256 B

    prep_atoms<<<dim3(CC),   dim3(256), 0, stream>>>(atoms, bfrag, can, kyy);
    mmd_fused <<<dim3(1024), dim3(256), 0, stream>>>(x, bfrag, can, kyy, out);
}